// Round 7
// baseline (3431.836 us; speedup 1.0000x reference)
//
#include <hip/hip_runtime.h>
#include <hip/hip_bf16.h>
#include <stdint.h>

#define DIM 4096
#define NB 4
#define SEQ 2048

typedef __bf16 bf16_t;
typedef __bf16 bf16x8 __attribute__((ext_vector_type(8)));
typedef float f32x4 __attribute__((ext_vector_type(4)));

__device__ __forceinline__ uint16_t f2bf_u(float f) {
  union { float f; uint32_t u; } v; v.f = f;
  uint32_t r = v.u + 0x7FFFu + ((v.u >> 16) & 1u);
  return (uint16_t)(r >> 16);
}

// ---------------- fp32 -> bf16 conversion ----------------
__global__ __launch_bounds__(256) void cvt_f32_bf16_k(const float* __restrict__ in,
                                                      uint16_t* __restrict__ out, long n) {
  long i = ((long)blockIdx.x * 256 + threadIdx.x) * 8;
  long stride = (long)gridDim.x * 256 * 8;
  for (; i < n; i += stride) {
    float4 a = *(const float4*)(in + i);
    float4 b = *(const float4*)(in + i + 4);
    ushort4 o0 = make_ushort4(f2bf_u(a.x), f2bf_u(a.y), f2bf_u(a.z), f2bf_u(a.w));
    ushort4 o1 = make_ushort4(f2bf_u(b.x), f2bf_u(b.y), f2bf_u(b.z), f2bf_u(b.w));
    *(ushort4*)(out + i) = o0;
    *(ushort4*)(out + i + 4) = o1;
  }
}

// ---------------- async global->LDS ----------------
__device__ __forceinline__ void gload16(const void* g, void* l) {
  __builtin_amdgcn_global_load_lds(
      (const __attribute__((address_space(1))) void*)g,
      (__attribute__((address_space(3))) void*)l,
      16, 0, 0);
}

#define BARX() do { asm volatile("" ::: "memory"); __builtin_amdgcn_s_barrier(); asm volatile("" ::: "memory"); } while (0)
#define VMW(n) asm volatile("s_waitcnt vmcnt(" #n ")" ::: "memory")

__device__ __forceinline__ void readA(bf16x8 (&fa)[4][2], const char* p, int c0, int c1) {
#pragma unroll
  for (int m = 0; m < 4; ++m) {
    fa[m][0] = *(const bf16x8*)(p + m * 2048 + c0);
    fa[m][1] = *(const bf16x8*)(p + m * 2048 + c1);
  }
}
__device__ __forceinline__ void readB(bf16x8 (&fb)[2][2], const char* p, int c0, int c1) {
#pragma unroll
  for (int n = 0; n < 2; ++n) {
    fb[n][0] = *(const bf16x8*)(p + n * 2048 + c0);
    fb[n][1] = *(const bf16x8*)(p + n * 2048 + c1);
  }
}
__device__ __forceinline__ void mmaQ(f32x4 (&acc)[4][2], const bf16x8 (&fa)[4][2],
                                     const bf16x8 (&fb)[2][2]) {
#pragma unroll
  for (int m = 0; m < 4; ++m)
#pragma unroll
    for (int n = 0; n < 2; ++n)
#pragma unroll
      for (int kk = 0; kk < 2; ++kk)
        acc[m][n] = __builtin_amdgcn_mfma_f32_16x16x32_bf16(fa[m][kk], fb[n][kk], acc[m][n], 0, 0, 0);
}
__device__ __forceinline__ void stageH(const bf16_t* gt, int soff, long rsk, char* lb, int t16) {
  gload16(gt + soff, lb + t16);
  gload16(gt + soff + rsk, lb + 8192 + t16);
}

#define PRIO1() __builtin_amdgcn_s_setprio(1)
#define PRIO0() __builtin_amdgcn_s_setprio(0)

// ---------- 256x256 8-region READ-AHEAD bf16 GEMM: C[m][n] = sum_k A[m][k]*B[n][k] --------
// Every ds_read fragment is issued 1-3 regions BEFORE its consuming MFMA, so each region's
// MFMA cluster starts immediately (operands already in regs) while the LDS unit services the
// next region's reads underneath it. Branch-free main loop (last iteration fully peeled).
// Quadrant order 00,01,11,10 per K-tile; 5 physical frag sets. 1 stageH per region; uniform
// VMW(4) at each region end retires stage(X-2) == exactly what region X+1's reads need.
// Prologue stages SIX halves (b0 all four + b1.A0 + b1.A1) -- b1.A1 was the round-6 bug.
// EPI 0: bf16 out  1: fp32 out  2: bf16( Xadd + silu(acc) )
template <int EPI>
__global__ __launch_bounds__(512, 2) void gemm256(
    const bf16_t* __restrict__ Abase, const bf16_t* __restrict__ Bbase,
    void* __restrict__ Cout, const float* __restrict__ Xadd,
    int M, int N, int K, long sA, long sB, long sC) {
  __shared__ char smem[131072];
  char* As = smem;            // [2 buf][A0:A1 halves][128 rows][64 K] bf16
  char* Bs = smem + 65536;

  const int tid = threadIdx.x;
  const int lane = tid & 63;
  const int wave = tid >> 6;
  const int wm = wave >> 2;   // 0..1  (row stripe)
  const int wn = wave & 3;    // 0..3  (col stripe)
  const int lr = lane & 15;
  const int hi = lane >> 4;

  // bijective XCD swizzle (all our grids are %8==0)
  const int nwg = gridDim.x;
  int wg = blockIdx.x;
  if ((nwg & 7) == 0) wg = (wg & 7) * (nwg >> 3) + (wg >> 3);
  const int nbn = N >> 8;
  const int bm = wg / nbn, bn = wg % nbn;

  const bf16_t* A = Abase + (long)blockIdx.y * sA;
  const bf16_t* B = Bbase + (long)blockIdx.y * sB;
  const bf16_t* A0p = A + (long)(bm * 256) * K;
  const bf16_t* A1p = A0p + (long)128 * K;
  const bf16_t* B0p = B + (long)(bn * 256) * K;
  const bf16_t* B1p = B0p + (long)128 * K;
  const long rsk = (long)64 * K;

  // staging: linear LDS dest, inverse-swizzled global source (3-bit XOR involution)
  const int t16 = tid * 16;
  const int lp = t16 ^ (((t16 >> 7) & 7) << 4);
  const int soff = (lp >> 7) * K + ((lp & 127) >> 1);

  // frag read addressing: row base + swizzled column (kk step applied via XOR 64)
  const int swz = (lr & 7) << 4;
  const int c0 = (hi * 16) ^ swz;
  const int c1 = c0 ^ 64;
  const int aR = (wm * 64 + lr) * 128;
  const int bR = (wn * 32 + lr) * 128;

  f32x4 acc[2][2][4][2] = {};
  bf16x8 fa0[4][2], fa1[4][2], fb0s0[2][2], fb0s1[2][2], fb1[2][2];

  // prologue: stage b0.{A0,B0,A1,B1} + b1.A0 + b1.A1 ; then read region-A operands
  stageH(A0p, soff, rsk, As, t16);               // b0.A0
  stageH(B0p, soff, rsk, Bs, t16);               // b0.B0
  stageH(A1p, soff, rsk, As + 16384, t16);       // b0.A1
  stageH(B1p, soff, rsk, Bs + 16384, t16);       // b0.B1
  stageH(A0p + 64, soff, rsk, As + 32768, t16);  // b1.A0
  stageH(A1p + 64, soff, rsk, As + 49152, t16);  // b1.A1  (the round-6 missing stage)
  VMW(4);   // all of b0 landed; b1.A0/b1.A1 in flight (retired at regions A/B)
  BARX();
  readA(fa0, As + aR, c0, c1);                   // b0.A0 frag
  readB(fb0s0, Bs + bR, c0, c1);                 // b0.B0 frag

  const int NIT = K >> 7;   // 2 K-tiles (of 64) per iteration
  for (int i = 0; i < NIT - 1; ++i) {
    const int kb1 = (2 * i + 1) * 64;   // buf1 tile this iter
    const int kb0n = kb1 + 64;          // next buf0 tile
    const int kb1n = kb1 + 128;         // next buf1 tile
    // A: M(00,b0) ; read b0.B1 ; stage b1.B0
    readB(fb1, Bs + 16384 + bR, c0, c1);
    stageH(B0p + kb1, soff, rsk, Bs + 32768, t16);
    PRIO1(); mmaQ(acc[0][0], fa0, fb0s0); PRIO0();
    VMW(4); BARX();                     // retires prev-G (b1.A0)
    // B: M(01,b0) ; read b0.A1 ; stage b1.B1
    readA(fa1, As + 16384 + aR, c0, c1);
    stageH(B1p + kb1, soff, rsk, Bs + 49152, t16);
    PRIO1(); mmaQ(acc[0][1], fa0, fb1); PRIO0();
    VMW(4); BARX();                     // retires prev-H (b1.A1)
    // C: M(11,b0) ; read b1.A0 ; stage b0'.A0
    readA(fa0, As + 32768 + aR, c0, c1);
    stageH(A0p + kb0n, soff, rsk, As, t16);
    PRIO1(); mmaQ(acc[1][1], fa1, fb1); PRIO0();
    VMW(4); BARX();                     // retires A's stage (b1.B0)
    // D: M(10,b0) ; read b1.B0 ; stage b0'.A1
    readB(fb0s1, Bs + 32768 + bR, c0, c1);
    stageH(A1p + kb0n, soff, rsk, As + 16384, t16);
    PRIO1(); mmaQ(acc[1][0], fa1, fb0s0); PRIO0();
    VMW(4); BARX();                     // retires B's stage (b1.B1)
    // E: M(00,b1) ; read b1.B1 ; stage b0'.B0
    readB(fb1, Bs + 49152 + bR, c0, c1);
    stageH(B0p + kb0n, soff, rsk, Bs, t16);
    PRIO1(); mmaQ(acc[0][0], fa0, fb0s1); PRIO0();
    VMW(4); BARX();                     // retires C's stage (b0'.A0)
    // F: M(01,b1) ; read b1.A1 ; stage b0'.B1
    readA(fa1, As + 49152 + aR, c0, c1);
    stageH(B1p + kb0n, soff, rsk, Bs + 16384, t16);
    PRIO1(); mmaQ(acc[0][1], fa0, fb1); PRIO0();
    VMW(4); BARX();                     // retires D's stage (b0'.A1)
    // G: M(11,b1) ; read b0'.A0 ; stage b1'.A0
    readA(fa0, As + aR, c0, c1);
    stageH(A0p + kb1n, soff, rsk, As + 32768, t16);
    PRIO1(); mmaQ(acc[1][1], fa1, fb1); PRIO0();
    VMW(4); BARX();                     // retires E's stage (b0'.B0)
    // H: M(10,b1) ; read b0'.B0 ; stage b1'.A1
    readB(fb0s0, Bs + bR, c0, c1);
    stageH(A1p + kb1n, soff, rsk, As + 49152, t16);
    PRIO1(); mmaQ(acc[1][0], fa1, fb0s1); PRIO0();
    VMW(4); BARX();                     // retires F's stage (b0'.B1)
  }
  // peeled last iteration (no next-tile stages or reads)
  {
    const int kb1 = (2 * (NIT - 1) + 1) * 64;
    // A
    readB(fb1, Bs + 16384 + bR, c0, c1);
    stageH(B0p + kb1, soff, rsk, Bs + 32768, t16);
    PRIO1(); mmaQ(acc[0][0], fa0, fb0s0); PRIO0();
    VMW(4); BARX();                      // retires prev-G (b1.A0)
    // B
    readA(fa1, As + 16384 + aR, c0, c1);
    stageH(B1p + kb1, soff, rsk, Bs + 49152, t16);
    PRIO1(); mmaQ(acc[0][1], fa0, fb1); PRIO0();
    VMW(4); BARX();                      // retires prev-H (b1.A1)
    // C
    readA(fa0, As + 32768 + aR, c0, c1);
    PRIO1(); mmaQ(acc[1][1], fa1, fb1); PRIO0();
    VMW(2); BARX();                      // retires A's stage (b1.B0)
    // D
    readB(fb0s1, Bs + 32768 + bR, c0, c1);
    PRIO1(); mmaQ(acc[1][0], fa1, fb0s0); PRIO0();
    VMW(0); BARX();                      // retires B's stage (b1.B1)
    // E
    readB(fb1, Bs + 49152 + bR, c0, c1);
    PRIO1(); mmaQ(acc[0][0], fa0, fb0s1); PRIO0();
    BARX();
    // F
    readA(fa1, As + 49152 + aR, c0, c1);
    PRIO1(); mmaQ(acc[0][1], fa0, fb1); PRIO0();
    BARX();
    // G
    PRIO1(); mmaQ(acc[1][1], fa1, fb1); PRIO0();
    // H
    PRIO1(); mmaQ(acc[1][0], fa1, fb0s1); PRIO0();
  }

  // epilogue: frag elem j -> row += j (D-layout: col=lane&15, row=(lane>>4)*4+j)
  const long cb = (long)blockIdx.y * sC;
#pragma unroll
  for (int mh = 0; mh < 2; ++mh)
#pragma unroll
    for (int nh = 0; nh < 2; ++nh)
#pragma unroll
      for (int m = 0; m < 4; ++m)
#pragma unroll
        for (int n = 0; n < 2; ++n)
#pragma unroll
          for (int j = 0; j < 4; ++j) {
            const int row = bm * 256 + mh * 128 + wm * 64 + m * 16 + hi * 4 + j;
            const int col = bn * 256 + nh * 128 + wn * 32 + n * 16 + lr;
            const long idx = cb + (long)row * N + col;
            const float vv = acc[mh][nh][m][n][j];
            if constexpr (EPI == 0) {
              ((uint16_t*)Cout)[idx] = f2bf_u(vv);
            } else if constexpr (EPI == 1) {
              ((float*)Cout)[idx] = vv;
            } else {
              const float sl = vv / (1.f + __expf(-vv));
              ((uint16_t*)Cout)[idx] = f2bf_u(Xadd[idx] + sl);
            }
          }
}

// ---------------- row softmax (4096 wide, fp32 -> bf16) ----------------
__global__ __launch_bounds__(256) void softmax_row4096(const float* __restrict__ in,
                                                       uint16_t* __restrict__ out) {
  const long row = blockIdx.x;
  const float* r = in + row * 4096;
  const int tid = threadIdx.x;
  float v[16];
#pragma unroll
  for (int i = 0; i < 4; ++i) {
    float4 a = *(const float4*)(r + tid * 16 + i * 4);
    v[i * 4 + 0] = a.x; v[i * 4 + 1] = a.y; v[i * 4 + 2] = a.z; v[i * 4 + 3] = a.w;
  }
  float m = v[0];
#pragma unroll
  for (int j = 1; j < 16; ++j) m = fmaxf(m, v[j]);
#pragma unroll
  for (int o = 32; o; o >>= 1) m = fmaxf(m, __shfl_xor(m, o));
  __shared__ float red[8];
  if ((tid & 63) == 0) red[tid >> 6] = m;
  __syncthreads();
  m = fmaxf(fmaxf(red[0], red[1]), fmaxf(red[2], red[3]));
  float s = 0.f;
#pragma unroll
  for (int j = 0; j < 16; ++j) { v[j] = __expf(v[j] - m); s += v[j]; }
#pragma unroll
  for (int o = 32; o; o >>= 1) s += __shfl_xor(s, o);
  if ((tid & 63) == 0) red[4 + (tid >> 6)] = s;
  __syncthreads();
  s = (red[4] + red[5]) + (red[6] + red[7]);
  float inv = 1.f / s;
#pragma unroll
  for (int i = 0; i < 4; ++i) {
    ushort4 u = make_ushort4(f2bf_u(v[i * 4 + 0] * inv), f2bf_u(v[i * 4 + 1] * inv),
                             f2bf_u(v[i * 4 + 2] * inv), f2bf_u(v[i * 4 + 3] * inv));
    *(ushort4*)(out + row * 4096 + tid * 16 + i * 4) = u;
  }
}

// ---------------- per-row (max, 1/sum(exp)) stats ----------------
__global__ __launch_bounds__(256) void rowstat4096(const float* __restrict__ in,
                                                   float2* __restrict__ stats) {
  const long row = blockIdx.x;
  const float* r = in + row * 4096;
  const int tid = threadIdx.x;
  float v[16];
#pragma unroll
  for (int i = 0; i < 4; ++i) {
    float4 a = *(const float4*)(r + tid * 16 + i * 4);
    v[i * 4 + 0] = a.x; v[i * 4 + 1] = a.y; v[i * 4 + 2] = a.z; v[i * 4 + 3] = a.w;
  }
  float m = v[0];
#pragma unroll
  for (int j = 1; j < 16; ++j) m = fmaxf(m, v[j]);
#pragma unroll
  for (int o = 32; o; o >>= 1) m = fmaxf(m, __shfl_xor(m, o));
  __shared__ float red[8];
  if ((tid & 63) == 0) red[tid >> 6] = m;
  __syncthreads();
  m = fmaxf(fmaxf(red[0], red[1]), fmaxf(red[2], red[3]));
  float s = 0.f;
#pragma unroll
  for (int j = 0; j < 16; ++j) s += __expf(v[j] - m);
#pragma unroll
  for (int o = 32; o; o >>= 1) s += __shfl_xor(s, o);
  if ((tid & 63) == 0) red[4 + (tid >> 6)] = s;
  __syncthreads();
  if (tid == 0) {
    s = (red[4] + red[5]) + (red[6] + red[7]);
    stats[row] = make_float2(m, 1.f / s);
  }
}

// ---------------- fused softmax + transpose: out[e][d] = sm(in)[d][e] ----------------
__global__ __launch_bounds__(256) void transposeSM(const float* __restrict__ in,
                                                   const float2* __restrict__ stats,
                                                   uint16_t* __restrict__ out) {
  __shared__ uint16_t t[64][68];
  __shared__ float2 st[64];
  const int tid = threadIdx.x;
  const int bx = blockIdx.x, by = blockIdx.y;
  if (tid < 64) st[tid] = stats[by * 64 + tid];
  __syncthreads();
  const int tr = tid >> 4;
  const int tc4 = (tid & 15) * 4;
#pragma unroll
  for (int i = 0; i < 4; ++i) {
    const int r = tr + i * 16;
    const float2 ms = st[r];
    float4 v = *(const float4*)&in[(long)(by * 64 + r) * 4096 + bx * 64 + tc4];
    t[r][tc4 + 0] = f2bf_u(__expf(v.x - ms.x) * ms.y);
    t[r][tc4 + 1] = f2bf_u(__expf(v.y - ms.x) * ms.y);
    t[r][tc4 + 2] = f2bf_u(__expf(v.z - ms.x) * ms.y);
    t[r][tc4 + 3] = f2bf_u(__expf(v.w - ms.x) * ms.y);
  }
  __syncthreads();
#pragma unroll
  for (int i = 0; i < 4; ++i) {
    const int oc = tr + i * 16;
    ushort4 v = make_ushort4(t[tc4 + 0][oc], t[tc4 + 1][oc], t[tc4 + 2][oc], t[tc4 + 3][oc]);
    *(ushort4*)&out[(long)(bx * 64 + oc) * 4096 + by * 64 + tc4] = v;
  }
}

// ---------------- host ----------------
extern "C" void kernel_launch(void* const* d_in, const int* in_sizes, int n_in,
                              void* d_out, int out_size, void* d_ws, size_t ws_size,
                              hipStream_t stream) {
  const float* x  = (const float*)d_in[0];
  const float* W1 = (const float*)d_in[1];
  const float* W2 = (const float*)d_in[2];
  const float* W3 = (const float*)d_in[3];
  const float* W4 = (const float*)d_in[4];
  const float* Wo = (const float*)d_in[5];

  char* ws = (char*)d_ws;
  const long SD  = (long)SEQ * DIM;
  const long BSD = (long)NB * SD;
  const long DD  = (long)DIM * DIM;

  // workspace layout (436,207,616 bytes == proven footprint)
  bf16_t* xbf  = (bf16_t*)(ws + 0L);           // x bf16; later y_in bf16
  bf16_t* xAT  = (bf16_t*)(ws + 67108864L);    // xA^T [b][d][s]
  bf16_t* xBT  = (bf16_t*)(ws + 134217728L);   // xB^T [b][e][s]; later xO_sm
  void*   R3   = (void*)  (ws + 201326592L);   // SQ fp32 (per batch); later xC bf16
  bf16_t* Wbf  = (bf16_t*)(ws + 268435456L);   // current weight bf16
  bf16_t* sqmT = (bf16_t*)(ws + 301989888L);   // softmax(sq)^T bf16 [4][e][d]
  float2* stats = (float2*)d_out;              // transient per-batch row stats
  float*  xOraw = (float*)d_out;               // xO raw fp32 (full d_out)
  (void)ws_size; (void)in_sizes; (void)n_in; (void)out_size;

  cvt_f32_bf16_k<<<2048, 256, 0, stream>>>(x, (uint16_t*)xbf, BSD);

  // xA^T[b][d][s] = W1 @ x_b^T   (batched, grid.y = 4)
  cvt_f32_bf16_k<<<2048, 256, 0, stream>>>(W1, (uint16_t*)Wbf, DD);
  gemm256<0><<<dim3(128, 4), 512, 0, stream>>>(Wbf, xbf, (void*)xAT, nullptr,
                                               DIM, SEQ, DIM, 0, SD, SD);
  // xB^T
  cvt_f32_bf16_k<<<2048, 256, 0, stream>>>(W2, (uint16_t*)Wbf, DD);
  gemm256<0><<<dim3(128, 4), 512, 0, stream>>>(Wbf, xbf, (void*)xBT, nullptr,
                                               DIM, SEQ, DIM, 0, SD, SD);

  // per batch: SQ = xA^T @ xB, softmax rows, transposed bf16 -> sqmT[b]
  for (int b = 0; b < NB; ++b) {
    gemm256<1><<<dim3(256, 1), 512, 0, stream>>>(xAT + b * SD, xBT + b * SD, R3, nullptr,
                                                 DIM, DIM, SEQ, 0, 0, 0);
    rowstat4096<<<DIM, 256, 0, stream>>>((const float*)R3, stats);
    transposeSM<<<dim3(64, 64), 256, 0, stream>>>((const float*)R3, stats,
                                                  (uint16_t*)(sqmT + b * DD));
  }

  // xC = x @ W3^T  (batch folded into M) -> R3 (SQ scratch dead)
  cvt_f32_bf16_k<<<2048, 256, 0, stream>>>(W3, (uint16_t*)Wbf, DD);
  gemm256<0><<<dim3(512, 1), 512, 0, stream>>>(xbf, Wbf, R3, nullptr,
                                               NB * SEQ, DIM, DIM, 0, 0, 0);

  // xO[b][s][e] = xC_b @ sqmT_b^T  (batched) -> d_out fp32 scratch
  gemm256<1><<<dim3(128, 4), 512, 0, stream>>>((const bf16_t*)R3, sqmT, (void*)xOraw, nullptr,
                                               SEQ, DIM, DIM, SD, DD, SD);
  // softmax rows of xO -> xO_sm bf16 (overwrites xBT)
  softmax_row4096<<<NB * SEQ, 256, 0, stream>>>(xOraw, (uint16_t*)xBT);

  // y_in = bf16( x + silu(xO_sm @ W4^T) ) -> xbf region
  cvt_f32_bf16_k<<<2048, 256, 0, stream>>>(W4, (uint16_t*)Wbf, DD);
  gemm256<2><<<dim3(512, 1), 512, 0, stream>>>(xBT, Wbf, (void*)xbf, x,
                                               NB * SEQ, DIM, DIM, 0, 0, 0);

  // out = y_in @ Wo^T (fp32)
  cvt_f32_bf16_k<<<2048, 256, 0, stream>>>(Wo, (uint16_t*)Wbf, DD);
  gemm256<1><<<dim3(512, 1), 512, 0, stream>>>(xbf, Wbf, d_out, nullptr,
                                               NB * SEQ, DIM, DIM, 0, 0, 0);
}

// Round 9
// 1730.464 us; speedup vs baseline: 1.9832x; 1.9832x over previous
//
#include <hip/hip_runtime.h>
#include <hip/hip_bf16.h>
#include <stdint.h>

#define DIM 4096
#define NB 4
#define SEQ 2048

typedef __bf16 bf16_t;
typedef __bf16 bf16x8 __attribute__((ext_vector_type(8)));
typedef float f32x4 __attribute__((ext_vector_type(4)));

__device__ __forceinline__ uint16_t f2bf_u(float f) {
  union { float f; uint32_t u; } v; v.f = f;
  uint32_t r = v.u + 0x7FFFu + ((v.u >> 16) & 1u);
  return (uint16_t)(r >> 16);
}
__device__ __forceinline__ float bfu2f(uint32_t u) {
  union { uint32_t u; float f; } v; v.u = u << 16; return v.f;
}

// ---------------- fp32 -> bf16 conversion ----------------
__global__ __launch_bounds__(256) void cvt_f32_bf16_k(const float* __restrict__ in,
                                                      uint16_t* __restrict__ out, long n) {
  long i = ((long)blockIdx.x * 256 + threadIdx.x) * 8;
  long stride = (long)gridDim.x * 256 * 8;
  for (; i < n; i += stride) {
    float4 a = *(const float4*)(in + i);
    float4 b = *(const float4*)(in + i + 4);
    ushort4 o0 = make_ushort4(f2bf_u(a.x), f2bf_u(a.y), f2bf_u(a.z), f2bf_u(a.w));
    ushort4 o1 = make_ushort4(f2bf_u(b.x), f2bf_u(b.y), f2bf_u(b.z), f2bf_u(b.w));
    *(ushort4*)(out + i) = o0;
    *(ushort4*)(out + i + 4) = o1;
  }
}

// ---------------- async global->LDS ----------------
__device__ __forceinline__ void gload16(const void* g, void* l) {
  __builtin_amdgcn_global_load_lds(
      (const __attribute__((address_space(1))) void*)g,
      (__attribute__((address_space(3))) void*)l,
      16, 0, 0);
}

#define BARX() do { asm volatile("" ::: "memory"); __builtin_amdgcn_s_barrier(); asm volatile("" ::: "memory"); } while (0)
#define VMW(n) asm volatile("s_waitcnt vmcnt(" #n ")" ::: "memory")

__device__ __forceinline__ void readA(bf16x8 (&fa)[4][2], const char* p, int c0, int c1) {
#pragma unroll
  for (int m = 0; m < 4; ++m) {
    fa[m][0] = *(const bf16x8*)(p + m * 2048 + c0);
    fa[m][1] = *(const bf16x8*)(p + m * 2048 + c1);
  }
}
__device__ __forceinline__ void readB(bf16x8 (&fb)[2][2], const char* p, int c0, int c1) {
#pragma unroll
  for (int n = 0; n < 2; ++n) {
    fb[n][0] = *(const bf16x8*)(p + n * 2048 + c0);
    fb[n][1] = *(const bf16x8*)(p + n * 2048 + c1);
  }
}
__device__ __forceinline__ void mmaQ(f32x4 (&acc)[4][2], const bf16x8 (&fa)[4][2],
                                     const bf16x8 (&fb)[2][2]) {
#pragma unroll
  for (int m = 0; m < 4; ++m)
#pragma unroll
    for (int n = 0; n < 2; ++n)
#pragma unroll
      for (int kk = 0; kk < 2; ++kk)
        acc[m][n] = __builtin_amdgcn_mfma_f32_16x16x32_bf16(fa[m][kk], fb[n][kk], acc[m][n], 0, 0, 0);
}
__device__ __forceinline__ void stageH(const bf16_t* gt, int soff, long rsk, char* lb, int t16) {
  gload16(gt + soff, lb + t16);
  gload16(gt + soff + rsk, lb + 8192 + t16);
}

#define PRIO1() __builtin_amdgcn_s_setprio(1)
#define PRIO0() __builtin_amdgcn_s_setprio(0)

// ---------------- 256x256 8-phase bf16 GEMM (round-3 PROVEN structure, unchanged) --------
// C[m][n] = sum_k A[m][k]*B[n][k]; 3-bit XOR swizzle both-sides, counted vmcnt at ph4/ph8,
// in-phase read->MFMA consumption (lgkm drains each phase => WAR-safe at every barrier).
// EPI 0: bf16 out  1: fp32 out  2: bf16( Xadd + silu(acc) )
template <int EPI>
__global__ __launch_bounds__(512, 2) void gemm256(
    const bf16_t* __restrict__ Abase, const bf16_t* __restrict__ Bbase,
    void* __restrict__ Cout, const float* __restrict__ Xadd,
    int M, int N, int K, long sA, long sB, long sC) {
  __shared__ char smem[131072];
  char* As = smem;            // [2 buf][2 half][128 rows][64 cols] bf16
  char* Bs = smem + 65536;

  const int tid = threadIdx.x;
  const int lane = tid & 63;
  const int wave = tid >> 6;
  const int wm = wave >> 2;   // 0..1  (row stripe)
  const int wn = wave & 3;    // 0..3  (col stripe)
  const int lr = lane & 15;
  const int hi = lane >> 4;

  // bijective XCD swizzle (all our grids are %8==0)
  const int nwg = gridDim.x;
  int wg = blockIdx.x;
  if ((nwg & 7) == 0) wg = (wg & 7) * (nwg >> 3) + (wg >> 3);
  const int nbn = N >> 8;
  const int bm = wg / nbn, bn = wg % nbn;

  const bf16_t* A = Abase + (long)blockIdx.y * sA;
  const bf16_t* B = Bbase + (long)blockIdx.y * sB;
  const bf16_t* A0p = A + (long)(bm * 256) * K;
  const bf16_t* A1p = A0p + (long)128 * K;
  const bf16_t* B0p = B + (long)(bn * 256) * K;
  const bf16_t* B1p = B0p + (long)128 * K;
  const long rsk = (long)64 * K;

  // staging: linear LDS dest, inverse-swizzled global source (3-bit XOR involution)
  const int t16 = tid * 16;
  const int lp = t16 ^ (((t16 >> 7) & 7) << 4);
  const int soff = (lp >> 7) * K + ((lp & 127) >> 1);

  // frag read addressing: row base + swizzled column (kk step applied via XOR 64)
  const int swz = (lr & 7) << 4;
  const int c0 = (hi * 16) ^ swz;
  const int c1 = c0 ^ 64;
  const int aR = (wm * 64 + lr) * 128;
  const int bR = (wn * 32 + lr) * 128;

  f32x4 acc[2][2][4][2] = {};
  bf16x8 fa0[4][2], fa1[4][2], fb0[2][2], fb1[2][2];

  // prologue: tile0 -> buf0 (4 halves), tile1 -> buf1 (A0,A1,B0)
  stageH(A0p, soff, rsk, As, t16);
  stageH(A1p, soff, rsk, As + 16384, t16);
  stageH(B0p, soff, rsk, Bs, t16);
  stageH(B1p, soff, rsk, Bs + 16384, t16);
  VMW(4);
  stageH(A0p + 64, soff, rsk, As + 32768, t16);
  stageH(A1p + 64, soff, rsk, As + 49152, t16);
  stageH(B0p + 64, soff, rsk, Bs + 32768, t16);
  VMW(6);
  BARX();

  const int NIT = K >> 7;   // 2 K-tiles (of 64) per iteration
  for (int i = 0; i < NIT; ++i) {
    const bool last = (i == NIT - 1);
    const int k1 = (2 * i + 1) * 64;
    // ph1
    readA(fa0, As + aR, c0, c1);
    readB(fb0, Bs + bR, c0, c1);
    stageH(B1p + k1, soff, rsk, Bs + 49152, t16);
    BARX();
    PRIO1(); mmaQ(acc[0][0], fa0, fb0); PRIO0();
    BARX();
    // ph2
    readA(fa1, As + 16384 + aR, c0, c1);
    if (!last) stageH(A0p + k1 + 64, soff, rsk, As, t16);
    BARX();
    PRIO1(); mmaQ(acc[1][0], fa1, fb0); PRIO0();
    BARX();
    // ph3
    readB(fb1, Bs + 16384 + bR, c0, c1);
    if (!last) stageH(A1p + k1 + 64, soff, rsk, As + 16384, t16);
    BARX();
    PRIO1(); mmaQ(acc[0][1], fa0, fb1); PRIO0();
    BARX();
    // ph4
    if (!last) stageH(B0p + k1 + 64, soff, rsk, Bs, t16);
    BARX();
    PRIO1(); mmaQ(acc[1][1], fa1, fb1); PRIO0();
    if (last) { VMW(0); } else { VMW(6); }
    BARX();
    // ph5
    readA(fa0, As + 32768 + aR, c0, c1);
    readB(fb0, Bs + 32768 + bR, c0, c1);
    if (!last) stageH(B1p + k1 + 64, soff, rsk, Bs + 16384, t16);
    BARX();
    PRIO1(); mmaQ(acc[0][0], fa0, fb0); PRIO0();
    BARX();
    // ph6
    readA(fa1, As + 49152 + aR, c0, c1);
    if (!last) stageH(A0p + k1 + 128, soff, rsk, As + 32768, t16);
    BARX();
    PRIO1(); mmaQ(acc[1][0], fa1, fb0); PRIO0();
    BARX();
    // ph7
    readB(fb1, Bs + 49152 + bR, c0, c1);
    if (!last) stageH(A1p + k1 + 128, soff, rsk, As + 49152, t16);
    BARX();
    PRIO1(); mmaQ(acc[0][1], fa0, fb1); PRIO0();
    BARX();
    // ph8
    if (!last) stageH(B0p + k1 + 128, soff, rsk, Bs + 32768, t16);
    BARX();
    PRIO1(); mmaQ(acc[1][1], fa1, fb1); PRIO0();
    if (!last) VMW(6);
    BARX();
  }

  // epilogue: frag elem j -> row += j (D-layout: col=lane&15, row=(lane>>4)*4+j)
  const long cb = (long)blockIdx.y * sC;
#pragma unroll
  for (int mh = 0; mh < 2; ++mh)
#pragma unroll
    for (int nh = 0; nh < 2; ++nh)
#pragma unroll
      for (int m = 0; m < 4; ++m)
#pragma unroll
        for (int n = 0; n < 2; ++n)
#pragma unroll
          for (int j = 0; j < 4; ++j) {
            const int row = bm * 256 + mh * 128 + wm * 64 + m * 16 + hi * 4 + j;
            const int col = bn * 256 + nh * 128 + wn * 32 + n * 16 + lr;
            const long idx = cb + (long)row * N + col;
            const float vv = acc[mh][nh][m][n][j];
            if constexpr (EPI == 0) {
              ((uint16_t*)Cout)[idx] = f2bf_u(vv);
            } else if constexpr (EPI == 1) {
              ((float*)Cout)[idx] = vv;
            } else {
              const float sl = vv / (1.f + __expf(-vv));
              ((uint16_t*)Cout)[idx] = f2bf_u(Xadd[idx] + sl);
            }
          }
}

// ------------- per-row (max, 1/sum(exp)) stats over bf16 rows of width 4096 -------------
__global__ __launch_bounds__(256) void rowstat4096_bf16(const uint16_t* __restrict__ in,
                                                        float2* __restrict__ stats) {
  const long row = blockIdx.x;
  const uint16_t* r = in + row * 4096;
  const int tid = threadIdx.x;
  uint32_t w[8];
  *(uint4*)(w) = *(const uint4*)(r + tid * 16);
  *(uint4*)(w + 4) = *(const uint4*)(r + tid * 16 + 8);
  float v[16];
#pragma unroll
  for (int j = 0; j < 8; ++j) {
    v[2 * j] = bfu2f(w[j] & 0xFFFFu);
    v[2 * j + 1] = bfu2f(w[j] >> 16);
  }
  float m = v[0];
#pragma unroll
  for (int j = 1; j < 16; ++j) m = fmaxf(m, v[j]);
#pragma unroll
  for (int o = 32; o; o >>= 1) m = fmaxf(m, __shfl_xor(m, o));
  __shared__ float red[8];
  if ((tid & 63) == 0) red[tid >> 6] = m;
  __syncthreads();
  m = fmaxf(fmaxf(red[0], red[1]), fmaxf(red[2], red[3]));
  float s = 0.f;
#pragma unroll
  for (int j = 0; j < 16; ++j) s += __expf(v[j] - m);
#pragma unroll
  for (int o = 32; o; o >>= 1) s += __shfl_xor(s, o);
  if ((tid & 63) == 0) red[4 + (tid >> 6)] = s;
  __syncthreads();
  if (tid == 0) {
    s = (red[4] + red[5]) + (red[6] + red[7]);
    stats[row] = make_float2(m, 1.f / s);
  }
}

// ------ fused softmax + transpose (bf16 in/out): out[b][e][d] = sm(in[b])[d][e] ------
__global__ __launch_bounds__(256) void transposeSM_bf16(const uint16_t* __restrict__ inB,
                                                        const float2* __restrict__ statsB,
                                                        uint16_t* __restrict__ outB) {
  const int b = blockIdx.z;
  const uint16_t* in = inB + (long)b * (4096L * 4096);
  const float2* stats = statsB + (long)b * 4096;
  uint16_t* out = outB + (long)b * (4096L * 4096);
  __shared__ uint16_t t[64][68];
  __shared__ float2 st[64];
  const int tid = threadIdx.x;
  const int bx = blockIdx.x, by = blockIdx.y;
  if (tid < 64) st[tid] = stats[by * 64 + tid];
  __syncthreads();
  const int tr = tid >> 4;
  const int tc4 = (tid & 15) * 4;
#pragma unroll
  for (int i = 0; i < 4; ++i) {
    const int r = tr + i * 16;
    const float2 ms = st[r];
    ushort4 u = *(const ushort4*)&in[(long)(by * 64 + r) * 4096 + bx * 64 + tc4];
    t[r][tc4 + 0] = f2bf_u(__expf(bfu2f(u.x) - ms.x) * ms.y);
    t[r][tc4 + 1] = f2bf_u(__expf(bfu2f(u.y) - ms.x) * ms.y);
    t[r][tc4 + 2] = f2bf_u(__expf(bfu2f(u.z) - ms.x) * ms.y);
    t[r][tc4 + 3] = f2bf_u(__expf(bfu2f(u.w) - ms.x) * ms.y);
  }
  __syncthreads();
#pragma unroll
  for (int i = 0; i < 4; ++i) {
    const int oc = tr + i * 16;
    ushort4 v = make_ushort4(t[tc4 + 0][oc], t[tc4 + 1][oc], t[tc4 + 2][oc], t[tc4 + 3][oc]);
    *(ushort4*)&out[(long)(bx * 64 + oc) * 4096 + by * 64 + tc4] = v;
  }
}

// ---------------- row softmax (bf16 in, bf16 out, width 4096) ----------------
__global__ __launch_bounds__(256) void softmax_row4096_bf16(const uint16_t* __restrict__ in,
                                                            uint16_t* __restrict__ out) {
  const long row = blockIdx.x;
  const uint16_t* r = in + row * 4096;
  const int tid = threadIdx.x;
  uint32_t w[8];
  *(uint4*)(w) = *(const uint4*)(r + tid * 16);
  *(uint4*)(w + 4) = *(const uint4*)(r + tid * 16 + 8);
  float v[16];
#pragma unroll
  for (int j = 0; j < 8; ++j) {
    v[2 * j] = bfu2f(w[j] & 0xFFFFu);
    v[2 * j + 1] = bfu2f(w[j] >> 16);
  }
  float m = v[0];
#pragma unroll
  for (int j = 1; j < 16; ++j) m = fmaxf(m, v[j]);
#pragma unroll
  for (int o = 32; o; o >>= 1) m = fmaxf(m, __shfl_xor(m, o));
  __shared__ float red[8];
  if ((tid & 63) == 0) red[tid >> 6] = m;
  __syncthreads();
  m = fmaxf(fmaxf(red[0], red[1]), fmaxf(red[2], red[3]));
  float s = 0.f;
#pragma unroll
  for (int j = 0; j < 16; ++j) { v[j] = __expf(v[j] - m); s += v[j]; }
#pragma unroll
  for (int o = 32; o; o >>= 1) s += __shfl_xor(s, o);
  if ((tid & 63) == 0) red[4 + (tid >> 6)] = s;
  __syncthreads();
  s = (red[4] + red[5]) + (red[6] + red[7]);
  float inv = 1.f / s;
#pragma unroll
  for (int i = 0; i < 4; ++i) {
    ushort4 u = make_ushort4(f2bf_u(v[i * 4 + 0] * inv), f2bf_u(v[i * 4 + 1] * inv),
                             f2bf_u(v[i * 4 + 2] * inv), f2bf_u(v[i * 4 + 3] * inv));
    *(ushort4*)(out + row * 4096 + tid * 16 + i * 4) = u;
  }
}

// ---------------- host ----------------
extern "C" void kernel_launch(void* const* d_in, const int* in_sizes, int n_in,
                              void* d_out, int out_size, void* d_ws, size_t ws_size,
                              hipStream_t stream) {
  const float* x  = (const float*)d_in[0];
  const float* W1 = (const float*)d_in[1];
  const float* W2 = (const float*)d_in[2];
  const float* W3 = (const float*)d_in[3];
  const float* W4 = (const float*)d_in[4];
  const float* Wo = (const float*)d_in[5];

  char* ws = (char*)d_ws;
  const long SD  = (long)SEQ * DIM;   // 8,388,608
  const long BSD = (long)NB * SD;
  const long DD  = (long)DIM * DIM;   // 16,777,216

  // workspace layout (436,207,616 bytes == proven footprint)
  bf16_t* xbf  = (bf16_t*)(ws + 0L);           // 67 MB : x bf16; later y_in bf16
  bf16_t* xW   = (bf16_t*)(ws + 67108864L);    // 134 MB: [b][ xA^T | xB^T ]; later xO_sm (first 67MB)
  bf16_t* R3   = (bf16_t*)(ws + 201326592L);   // 67 MB : W1||W2 bf16; later xC bf16
  bf16_t* Wbf  = (bf16_t*)(ws + 268435456L);   // 33.5MB: stats (128KB) during sq; then W3/W4/Wo bf16
  bf16_t* sqmT = (bf16_t*)(ws + 301989888L);   // 134 MB: softmax(sq)^T bf16 [4][e][d]
  float2* stats = (float2*)Wbf;                // 16384 x float2, dead before W3 cvt
  (void)ws_size; (void)in_sizes; (void)n_in; (void)out_size;

  // x -> bf16
  cvt_f32_bf16_k<<<2048, 256, 0, stream>>>(x, (uint16_t*)xbf, BSD);

  // W1,W2 -> bf16 into R3 (concatenated: M = 8192 weight rows)
  cvt_f32_bf16_k<<<2048, 256, 0, stream>>>(W1, (uint16_t*)R3, DD);
  cvt_f32_bf16_k<<<2048, 256, 0, stream>>>(W2, (uint16_t*)(R3 + DD), DD);
  // merged G1+G2: xW[b] = (W1||W2) @ x_b^T   [b][2*4096][2048] bf16
  gemm256<0><<<dim3(256, 4), 512, 0, stream>>>(R3, xbf, (void*)xW, nullptr,
                                               2 * DIM, SEQ, DIM, 0, SD, 2 * SD);

  // batched sq: SQ_bf16[b][d][e] = xA_b^T @ xB_b  -> d_out (exactly 134 MB)
  gemm256<0><<<dim3(256, 4), 512, 0, stream>>>(xW, xW + SD, d_out, nullptr,
                                               DIM, DIM, SEQ, 2 * SD, 2 * SD, DD);
  // row stats over all 4*4096 rows
  rowstat4096_bf16<<<NB * DIM, 256, 0, stream>>>((const uint16_t*)d_out, stats);
  // fused softmax+transpose -> sqmT[b][e][d]
  transposeSM_bf16<<<dim3(64, 64, 4), 256, 0, stream>>>((const uint16_t*)d_out, stats,
                                                        (uint16_t*)sqmT);

  // xC = x @ W3^T  -> R3 (bf16, batch folded into M)
  cvt_f32_bf16_k<<<2048, 256, 0, stream>>>(W3, (uint16_t*)Wbf, DD);
  gemm256<0><<<dim3(512, 1), 512, 0, stream>>>(xbf, Wbf, (void*)R3, nullptr,
                                               NB * SEQ, DIM, DIM, 0, 0, 0);

  // xO[b][s][e] = xC_b @ sqmT_b^T  -> d_out (bf16, first 67 MB; SQ data dead)
  gemm256<0><<<dim3(128, 4), 512, 0, stream>>>(R3, sqmT, d_out, nullptr,
                                               SEQ, DIM, DIM, SD, DD, SD);
  // softmax rows of xO -> xO_sm bf16 into xW (dead after sq phase)
  softmax_row4096_bf16<<<NB * SEQ, 256, 0, stream>>>((const uint16_t*)d_out, (uint16_t*)xW);

  // y_in = bf16( x + silu(xO_sm @ W4^T) ) -> xbf
  cvt_f32_bf16_k<<<2048, 256, 0, stream>>>(W4, (uint16_t*)Wbf, DD);
  gemm256<2><<<dim3(512, 1), 512, 0, stream>>>(xW, Wbf, (void*)xbf, x,
                                               NB * SEQ, DIM, DIM, 0, 0, 0);

  // out = y_in @ Wo^T (fp32) -> d_out
  cvt_f32_bf16_k<<<2048, 256, 0, stream>>>(Wo, (uint16_t*)Wbf, DD);
  gemm256<1><<<dim3(512, 1), 512, 0, stream>>>(xbf, Wbf, d_out, nullptr,
                                               NB * SEQ, DIM, DIM, 0, 0, 0);
}

// Round 10
// 1684.970 us; speedup vs baseline: 2.0367x; 1.0270x over previous
//
#include <hip/hip_runtime.h>
#include <hip/hip_bf16.h>
#include <stdint.h>

#define DIM 4096
#define NB 4
#define SEQ 2048

typedef __bf16 bf16_t;
typedef __bf16 bf16x8 __attribute__((ext_vector_type(8)));
typedef float f32x4 __attribute__((ext_vector_type(4)));

__device__ __forceinline__ uint16_t f2bf_u(float f) {
  union { float f; uint32_t u; } v; v.f = f;
  uint32_t r = v.u + 0x7FFFu + ((v.u >> 16) & 1u);
  return (uint16_t)(r >> 16);
}
__device__ __forceinline__ float bfu2f(uint32_t u) {
  union { uint32_t u; float f; } v; v.u = u << 16; return v.f;
}

// ---------------- fp32 -> bf16 conversion ----------------
__global__ __launch_bounds__(256) void cvt_f32_bf16_k(const float* __restrict__ in,
                                                      uint16_t* __restrict__ out, long n) {
  long i = ((long)blockIdx.x * 256 + threadIdx.x) * 8;
  long stride = (long)gridDim.x * 256 * 8;
  for (; i < n; i += stride) {
    float4 a = *(const float4*)(in + i);
    float4 b = *(const float4*)(in + i + 4);
    ushort4 o0 = make_ushort4(f2bf_u(a.x), f2bf_u(a.y), f2bf_u(a.z), f2bf_u(a.w));
    ushort4 o1 = make_ushort4(f2bf_u(b.x), f2bf_u(b.y), f2bf_u(b.z), f2bf_u(b.w));
    *(ushort4*)(out + i) = o0;
    *(ushort4*)(out + i + 4) = o1;
  }
}

// ---------------- async global->LDS ----------------
__device__ __forceinline__ void gload16(const void* g, void* l) {
  __builtin_amdgcn_global_load_lds(
      (const __attribute__((address_space(1))) void*)g,
      (__attribute__((address_space(3))) void*)l,
      16, 0, 0);
}

#define BARX() do { asm volatile("" ::: "memory"); __builtin_amdgcn_s_barrier(); asm volatile("" ::: "memory"); } while (0)
#define VMW(n) asm volatile("s_waitcnt vmcnt(" #n ")" ::: "memory")
#define LGKM(n) asm volatile("s_waitcnt lgkmcnt(" #n ")" ::: "memory")

__device__ __forceinline__ void readA(bf16x8 (&fa)[4][2], const char* p, int c0, int c1) {
#pragma unroll
  for (int m = 0; m < 4; ++m) {
    fa[m][0] = *(const bf16x8*)(p + m * 2048 + c0);
    fa[m][1] = *(const bf16x8*)(p + m * 2048 + c1);
  }
}
__device__ __forceinline__ void readB(bf16x8 (&fb)[2][2], const char* p, int c0, int c1) {
#pragma unroll
  for (int n = 0; n < 2; ++n) {
    fb[n][0] = *(const bf16x8*)(p + n * 2048 + c0);
    fb[n][1] = *(const bf16x8*)(p + n * 2048 + c1);
  }
}
__device__ __forceinline__ void mmaQ(f32x4 (&acc)[4][2], const bf16x8 (&fa)[4][2],
                                     const bf16x8 (&fb)[2][2]) {
#pragma unroll
  for (int m = 0; m < 4; ++m)
#pragma unroll
    for (int n = 0; n < 2; ++n)
#pragma unroll
      for (int kk = 0; kk < 2; ++kk)
        acc[m][n] = __builtin_amdgcn_mfma_f32_16x16x32_bf16(fa[m][kk], fb[n][kk], acc[m][n], 0, 0, 0);
}
__device__ __forceinline__ void stageH(const bf16_t* gt, int soff, long rsk, char* lb, int t16) {
  gload16(gt + soff, lb + t16);
  gload16(gt + soff + rsk, lb + 8192 + t16);
}

#define PRIO1() __builtin_amdgcn_s_setprio(1)
#define PRIO0() __builtin_amdgcn_s_setprio(0)

// ---- 256x256 8-phase READ-NEXT bf16 GEMM: C[m][n] = sum_k A[m][k]*B[n][k] ----
// read@X -> consume@X+1: each phase's ds_reads execute on the LDS pipe while the
// current 16-MFMA cluster drains. FOUR frag sets (96 VGPR; 5th set spills).
// Stage schedule = read+2 for every region (ph1:A00 ph2:B00 ph3:B01 ph4:A01
// ph5:A10 ph6:B10 ph7:B11 ph8:A11); consumption@+1 forces lgkm drain before each
// overwrite; LGKM(4)@ph4/ph8 closes the two gap-2-consumption cases (fa0).
// vmcnt: queue-exact uniform VMW(10) BEFORE every barrier (cross-wave valid);
// prologue VMW(12); stages wrap k&(K-1) on last iter (wrapped reads are dead).
// EPI 0: bf16 out  1: fp32 out  2: bf16( Xadd + silu(acc) )
template <int EPI>
__global__ __launch_bounds__(512, 2) void gemm256(
    const bf16_t* __restrict__ Abase, const bf16_t* __restrict__ Bbase,
    void* __restrict__ Cout, const float* __restrict__ Xadd,
    int M, int N, int K, long sA, long sB, long sC) {
  __shared__ char smem[131072];
  char* As = smem;            // [A00 | A01 | A10 | A11] x 16KB
  char* Bs = smem + 65536;    // [B00 | B01 | B10 | B11] x 16KB

  const int tid = threadIdx.x;
  const int lane = tid & 63;
  const int wave = tid >> 6;
  const int wm = wave >> 2;   // 0..1  (row stripe)
  const int wn = wave & 3;    // 0..3  (col stripe)
  const int lr = lane & 15;
  const int hi = lane >> 4;

  // bijective XCD swizzle (all our grids are %8==0)
  const int nwg = gridDim.x;
  int wg = blockIdx.x;
  if ((nwg & 7) == 0) wg = (wg & 7) * (nwg >> 3) + (wg >> 3);
  const int nbn = N >> 8;
  const int bm = wg / nbn, bn = wg % nbn;

  const bf16_t* A = Abase + (long)blockIdx.y * sA;
  const bf16_t* B = Bbase + (long)blockIdx.y * sB;
  const bf16_t* A0p = A + (long)(bm * 256) * K;
  const bf16_t* A1p = A0p + (long)128 * K;
  const bf16_t* B0p = B + (long)(bn * 256) * K;
  const bf16_t* B1p = B0p + (long)128 * K;
  const long rsk = (long)64 * K;

  // staging: linear LDS dest, inverse-swizzled global source (3-bit XOR involution)
  const int t16 = tid * 16;
  const int lp = t16 ^ (((t16 >> 7) & 7) << 4);
  const int soff = (lp >> 7) * K + ((lp & 127) >> 1);

  // frag read addressing: row base + swizzled column (kk step applied via XOR 64)
  const int swz = (lr & 7) << 4;
  const int c0 = (hi * 16) ^ swz;
  const int c1 = c0 ^ 64;
  const int aR = (wm * 64 + lr) * 128;
  const int bR = (wn * 32 + lr) * 128;

  f32x4 acc[2][2][4][2] = {};
  bf16x8 fa0[4][2], fa1[4][2], fb0[2][2], fb1[2][2];

  // prologue: stage tiles 0 (b0 regions) and 1 (b1 regions), queue order matters
  stageH(A0p, soff, rsk, As, t16);                // A00  (t0)
  stageH(B0p, soff, rsk, Bs, t16);                // B00  (t0)
  stageH(B1p, soff, rsk, Bs + 16384, t16);        // B01  (t0)
  stageH(A1p, soff, rsk, As + 16384, t16);        // A01  (t0)
  stageH(A0p + 64, soff, rsk, As + 32768, t16);   // A10  (t1)
  stageH(B0p + 64, soff, rsk, Bs + 32768, t16);   // B10  (t1)
  stageH(B1p + 64, soff, rsk, Bs + 49152, t16);   // B11  (t1)
  stageH(A1p + 64, soff, rsk, As + 49152, t16);   // A11  (t1)
  VMW(12);                                        // A00,B00 landed
  BARX();
  readA(fa0, As + aR, c0, c1);                    // A00 frag (for ph1)
  readB(fb0, Bs + bR, c0, c1);                    // B00 frag (for ph1)
  LGKM(0);                                        // drain pre-loop reads (ph1 stages A00)
  VMW(10);                                        // B01 landed (ph1 reads it)
  BARX();

  const int NIT = K >> 7;   // 2 K-tiles (of 64) per iteration
  const int kmask = K - 1;  // K is a power of two
  for (int i = 0; i < NIT; ++i) {
    const int k2 = (128 * i + 128) & kmask;  // next b0 tile (wraps on last iter: dead)
    const int k3 = (128 * i + 192) & kmask;  // next b1 tile

    // ph1: Q00(b0)[fa0,fb0] ; read fb1<-B01 ; stage A00<-k2
    readB(fb1, Bs + 16384 + bR, c0, c1);
    stageH(A0p + k2, soff, rsk, As, t16);
    PRIO1(); mmaQ(acc[0][0], fa0, fb0); PRIO0();
    VMW(10); BARX();
    // ph2: Q01(b0)[fa0,fb1] ; read fa1<-A01 ; stage B00<-k2
    readA(fa1, As + 16384 + aR, c0, c1);
    stageH(B0p + k2, soff, rsk, Bs, t16);
    PRIO1(); mmaQ(acc[0][1], fa0, fb1); PRIO0();
    VMW(10); BARX();
    // ph3: Q11(b0)[fa1,fb1] ; read fa0<-A10 ; stage B01<-k2
    readA(fa0, As + 32768 + aR, c0, c1);
    stageH(B1p + k2, soff, rsk, Bs + 16384, t16);
    PRIO1(); mmaQ(acc[1][1], fa1, fb1); PRIO0();
    VMW(10); BARX();
    // ph4: Q10(b0)[fa1,fb0] ; THEN read fb0<-B10 (reg WAR) ; stage A01<-k2 ; LGKM(4)
    PRIO1(); mmaQ(acc[1][0], fa1, fb0); PRIO0();
    readB(fb0, Bs + 32768 + bR, c0, c1);
    stageH(A1p + k2, soff, rsk, As + 16384, t16);
    LGKM(4);   // drain ph3's fa0 reads (A10 is staged at ph5)
    VMW(10); BARX();
    // ph5: Q00(b1)[fa0,fb0] ; read fb1<-B11 ; stage A10<-k3
    readB(fb1, Bs + 49152 + bR, c0, c1);
    stageH(A0p + k3, soff, rsk, As + 32768, t16);
    PRIO1(); mmaQ(acc[0][0], fa0, fb0); PRIO0();
    VMW(10); BARX();
    // ph6: Q01(b1)[fa0,fb1] ; read fa1<-A11 ; stage B10<-k3
    readA(fa1, As + 49152 + aR, c0, c1);
    stageH(B0p + k3, soff, rsk, Bs + 32768, t16);
    PRIO1(); mmaQ(acc[0][1], fa0, fb1); PRIO0();
    VMW(10); BARX();
    // ph7: Q11(b1)[fa1,fb1] ; read fa0<-A00(next) ; stage B11<-k3
    readA(fa0, As + aR, c0, c1);
    stageH(B1p + k3, soff, rsk, Bs + 49152, t16);
    PRIO1(); mmaQ(acc[1][1], fa1, fb1); PRIO0();
    VMW(10); BARX();
    // ph8: Q10(b1)[fa1,fb0] ; THEN read fb0<-B00(next) ; stage A11<-k3 ; LGKM(4)
    PRIO1(); mmaQ(acc[1][0], fa1, fb0); PRIO0();
    readB(fb0, Bs + bR, c0, c1);
    stageH(A1p + k3, soff, rsk, As + 49152, t16);
    LGKM(4);   // drain ph7's fa0 reads (A00 is staged at next ph1)
    VMW(10); BARX();
  }

  // epilogue: frag elem j -> row += j (D-layout: col=lane&15, row=(lane>>4)*4+j)
  const long cb = (long)blockIdx.y * sC;
#pragma unroll
  for (int mh = 0; mh < 2; ++mh)
#pragma unroll
    for (int nh = 0; nh < 2; ++nh)
#pragma unroll
      for (int m = 0; m < 4; ++m)
#pragma unroll
        for (int n = 0; n < 2; ++n)
#pragma unroll
          for (int j = 0; j < 4; ++j) {
            const int row = bm * 256 + mh * 128 + wm * 64 + m * 16 + hi * 4 + j;
            const int col = bn * 256 + nh * 128 + wn * 32 + n * 16 + lr;
            const long idx = cb + (long)row * N + col;
            const float vv = acc[mh][nh][m][n][j];
            if constexpr (EPI == 0) {
              ((uint16_t*)Cout)[idx] = f2bf_u(vv);
            } else if constexpr (EPI == 1) {
              ((float*)Cout)[idx] = vv;
            } else {
              const float sl = vv / (1.f + __expf(-vv));
              ((uint16_t*)Cout)[idx] = f2bf_u(Xadd[idx] + sl);
            }
          }
}

// ------------- per-row (max, 1/sum(exp)) stats over bf16 rows of width 4096 -------------
__global__ __launch_bounds__(256) void rowstat4096_bf16(const uint16_t* __restrict__ in,
                                                        float2* __restrict__ stats) {
  const long row = blockIdx.x;
  const uint16_t* r = in + row * 4096;
  const int tid = threadIdx.x;
  uint32_t w[8];
  *(uint4*)(w) = *(const uint4*)(r + tid * 16);
  *(uint4*)(w + 4) = *(const uint4*)(r + tid * 16 + 8);
  float v[16];
#pragma unroll
  for (int j = 0; j < 8; ++j) {
    v[2 * j] = bfu2f(w[j] & 0xFFFFu);
    v[2 * j + 1] = bfu2f(w[j] >> 16);
  }
  float m = v[0];
#pragma unroll
  for (int j = 1; j < 16; ++j) m = fmaxf(m, v[j]);
#pragma unroll
  for (int o = 32; o; o >>= 1) m = fmaxf(m, __shfl_xor(m, o));
  __shared__ float red[8];
  if ((tid & 63) == 0) red[tid >> 6] = m;
  __syncthreads();
  m = fmaxf(fmaxf(red[0], red[1]), fmaxf(red[2], red[3]));
  float s = 0.f;
#pragma unroll
  for (int j = 0; j < 16; ++j) s += __expf(v[j] - m);
#pragma unroll
  for (int o = 32; o; o >>= 1) s += __shfl_xor(s, o);
  if ((tid & 63) == 0) red[4 + (tid >> 6)] = s;
  __syncthreads();
  if (tid == 0) {
    s = (red[4] + red[5]) + (red[6] + red[7]);
    stats[row] = make_float2(m, 1.f / s);
  }
}

// ------ fused softmax + transpose (bf16 in/out): out[b][e][d] = sm(in[b])[d][e] ------
__global__ __launch_bounds__(256) void transposeSM_bf16(const uint16_t* __restrict__ inB,
                                                        const float2* __restrict__ statsB,
                                                        uint16_t* __restrict__ outB) {
  const int b = blockIdx.z;
  const uint16_t* in = inB + (long)b * (4096L * 4096);
  const float2* stats = statsB + (long)b * 4096;
  uint16_t* out = outB + (long)b * (4096L * 4096);
  __shared__ uint16_t t[64][68];
  __shared__ float2 st[64];
  const int tid = threadIdx.x;
  const int bx = blockIdx.x, by = blockIdx.y;
  if (tid < 64) st[tid] = stats[by * 64 + tid];
  __syncthreads();
  const int tr = tid >> 4;
  const int tc4 = (tid & 15) * 4;
#pragma unroll
  for (int i = 0; i < 4; ++i) {
    const int r = tr + i * 16;
    const float2 ms = st[r];
    ushort4 u = *(const ushort4*)&in[(long)(by * 64 + r) * 4096 + bx * 64 + tc4];
    t[r][tc4 + 0] = f2bf_u(__expf(bfu2f(u.x) - ms.x) * ms.y);
    t[r][tc4 + 1] = f2bf_u(__expf(bfu2f(u.y) - ms.x) * ms.y);
    t[r][tc4 + 2] = f2bf_u(__expf(bfu2f(u.z) - ms.x) * ms.y);
    t[r][tc4 + 3] = f2bf_u(__expf(bfu2f(u.w) - ms.x) * ms.y);
  }
  __syncthreads();
#pragma unroll
  for (int i = 0; i < 4; ++i) {
    const int oc = tr + i * 16;
    ushort4 v = make_ushort4(t[tc4 + 0][oc], t[tc4 + 1][oc], t[tc4 + 2][oc], t[tc4 + 3][oc]);
    *(ushort4*)&out[(long)(bx * 64 + oc) * 4096 + by * 64 + tc4] = v;
  }
}

// ---------------- row softmax (bf16 in, bf16 out, width 4096) ----------------
__global__ __launch_bounds__(256) void softmax_row4096_bf16(const uint16_t* __restrict__ in,
                                                            uint16_t* __restrict__ out) {
  const long row = blockIdx.x;
  const uint16_t* r = in + row * 4096;
  const int tid = threadIdx.x;
  uint32_t w[8];
  *(uint4*)(w) = *(const uint4*)(r + tid * 16);
  *(uint4*)(w + 4) = *(const uint4*)(r + tid * 16 + 8);
  float v[16];
#pragma unroll
  for (int j = 0; j < 8; ++j) {
    v[2 * j] = bfu2f(w[j] & 0xFFFFu);
    v[2 * j + 1] = bfu2f(w[j] >> 16);
  }
  float m = v[0];
#pragma unroll
  for (int j = 1; j < 16; ++j) m = fmaxf(m, v[j]);
#pragma unroll
  for (int o = 32; o; o >>= 1) m = fmaxf(m, __shfl_xor(m, o));
  __shared__ float red[8];
  if ((tid & 63) == 0) red[tid >> 6] = m;
  __syncthreads();
  m = fmaxf(fmaxf(red[0], red[1]), fmaxf(red[2], red[3]));
  float s = 0.f;
#pragma unroll
  for (int j = 0; j < 16; ++j) { v[j] = __expf(v[j] - m); s += v[j]; }
#pragma unroll
  for (int o = 32; o; o >>= 1) s += __shfl_xor(s, o);
  if ((tid & 63) == 0) red[4 + (tid >> 6)] = s;
  __syncthreads();
  s = (red[4] + red[5]) + (red[6] + red[7]);
  float inv = 1.f / s;
#pragma unroll
  for (int i = 0; i < 4; ++i) {
    ushort4 u = make_ushort4(f2bf_u(v[i * 4 + 0] * inv), f2bf_u(v[i * 4 + 1] * inv),
                             f2bf_u(v[i * 4 + 2] * inv), f2bf_u(v[i * 4 + 3] * inv));
    *(ushort4*)(out + row * 4096 + tid * 16 + i * 4) = u;
  }
}

// ---------------- host ----------------
extern "C" void kernel_launch(void* const* d_in, const int* in_sizes, int n_in,
                              void* d_out, int out_size, void* d_ws, size_t ws_size,
                              hipStream_t stream) {
  const float* x  = (const float*)d_in[0];
  const float* W1 = (const float*)d_in[1];
  const float* W2 = (const float*)d_in[2];
  const float* W3 = (const float*)d_in[3];
  const float* W4 = (const float*)d_in[4];
  const float* Wo = (const float*)d_in[5];

  char* ws = (char*)d_ws;
  const long SD  = (long)SEQ * DIM;   // 8,388,608
  const long BSD = (long)NB * SD;
  const long DD  = (long)DIM * DIM;   // 16,777,216

  // workspace layout (436,207,616 bytes == proven footprint)
  bf16_t* xbf  = (bf16_t*)(ws + 0L);           // 67 MB : x bf16; later y_in bf16
  bf16_t* xW   = (bf16_t*)(ws + 67108864L);    // 134 MB: [b][ xA^T | xB^T ]; later xO_sm
  bf16_t* R3   = (bf16_t*)(ws + 201326592L);   // 67 MB : W1||W2 bf16; later xC bf16
  bf16_t* Wbf  = (bf16_t*)(ws + 268435456L);   // 33.5MB: stats during sq; then W3/W4/Wo bf16
  bf16_t* sqmT = (bf16_t*)(ws + 301989888L);   // 134 MB: softmax(sq)^T bf16 [4][e][d]
  float2* stats = (float2*)Wbf;                // 16384 x float2, dead before W3 cvt
  (void)ws_size; (void)in_sizes; (void)n_in; (void)out_size;

  // x -> bf16
  cvt_f32_bf16_k<<<2048, 256, 0, stream>>>(x, (uint16_t*)xbf, BSD);

  // W1,W2 -> bf16 into R3 (concatenated: M = 8192 weight rows)
  cvt_f32_bf16_k<<<2048, 256, 0, stream>>>(W1, (uint16_t*)R3, DD);
  cvt_f32_bf16_k<<<2048, 256, 0, stream>>>(W2, (uint16_t*)(R3 + DD), DD);
  // merged G1+G2: xW[b] = (W1||W2) @ x_b^T   [b][2*4096][2048] bf16
  gemm256<0><<<dim3(256, 4), 512, 0, stream>>>(R3, xbf, (void*)xW, nullptr,
                                               2 * DIM, SEQ, DIM, 0, SD, 2 * SD);

  // batched sq: SQ_bf16[b][d][e] = xA_b^T @ xB_b  -> d_out (exactly 134 MB)
  gemm256<0><<<dim3(256, 4), 512, 0, stream>>>(xW, xW + SD, d_out, nullptr,
                                               DIM, DIM, SEQ, 2 * SD, 2 * SD, DD);
  // row stats over all 4*4096 rows
  rowstat4096_bf16<<<NB * DIM, 256, 0, stream>>>((const uint16_t*)d_out, stats);
  // fused softmax+transpose -> sqmT[b][e][d]
  transposeSM_bf16<<<dim3(64, 64, 4), 256, 0, stream>>>((const uint16_t*)d_out, stats,
                                                        (uint16_t*)sqmT);

  // xC = x @ W3^T  -> R3 (bf16, batch folded into M)
  cvt_f32_bf16_k<<<2048, 256, 0, stream>>>(W3, (uint16_t*)Wbf, DD);
  gemm256<0><<<dim3(512, 1), 512, 0, stream>>>(xbf, Wbf, (void*)R3, nullptr,
                                               NB * SEQ, DIM, DIM, 0, 0, 0);

  // xO[b][s][e] = xC_b @ sqmT_b^T  -> d_out (bf16, first 67 MB; SQ data dead)
  gemm256<0><<<dim3(128, 4), 512, 0, stream>>>(R3, sqmT, d_out, nullptr,
                                               SEQ, DIM, DIM, SD, DD, SD);
  // softmax rows of xO -> xO_sm bf16 into xW (dead after sq phase)
  softmax_row4096_bf16<<<NB * SEQ, 256, 0, stream>>>((const uint16_t*)d_out, (uint16_t*)xW);

  // y_in = bf16( x + silu(xO_sm @ W4^T) ) -> xbf
  cvt_f32_bf16_k<<<2048, 256, 0, stream>>>(W4, (uint16_t*)Wbf, DD);
  gemm256<2><<<dim3(512, 1), 512, 0, stream>>>(xW, Wbf, (void*)xbf, x,
                                               NB * SEQ, DIM, DIM, 0, 0, 0);

  // out = y_in @ Wo^T (fp32) -> d_out
  cvt_f32_bf16_k<<<2048, 256, 0, stream>>>(Wo, (uint16_t*)Wbf, DD);
  gemm256<1><<<dim3(512, 1), 512, 0, stream>>>(xbf, Wbf, d_out, nullptr,
                                               NB * SEQ, DIM, DIM, 0, 0, 0);
}

// Round 11
// 1677.279 us; speedup vs baseline: 2.0461x; 1.0046x over previous
//
#include <hip/hip_runtime.h>
#include <hip/hip_bf16.h>
#include <stdint.h>

#define DIM 4096
#define NB 4
#define SEQ 2048

typedef __bf16 bf16_t;
typedef __bf16 bf16x8 __attribute__((ext_vector_type(8)));
typedef float f32x4 __attribute__((ext_vector_type(4)));

__device__ __forceinline__ uint16_t f2bf_u(float f) {
  union { float f; uint32_t u; } v; v.f = f;
  uint32_t r = v.u + 0x7FFFu + ((v.u >> 16) & 1u);
  return (uint16_t)(r >> 16);
}
__device__ __forceinline__ float bfu2f(uint32_t u) {
  union { uint32_t u; float f; } v; v.u = u << 16; return v.f;
}

// ---------------- fp32 -> bf16 conversion, 3 tensors per launch ----------------
__global__ __launch_bounds__(256) void cvt3_f32_bf16_k(
    const float* __restrict__ s0, uint16_t* __restrict__ d0, long n0,
    const float* __restrict__ s1, uint16_t* __restrict__ d1, long n1,
    const float* __restrict__ s2, uint16_t* __restrict__ d2, long n2) {
  const float* s; uint16_t* d; long n;
  if (blockIdx.y == 0)      { s = s0; d = d0; n = n0; }
  else if (blockIdx.y == 1) { s = s1; d = d1; n = n1; }
  else                      { s = s2; d = d2; n = n2; }
  long i = ((long)blockIdx.x * 256 + threadIdx.x) * 8;
  long stride = (long)gridDim.x * 256 * 8;
  for (; i < n; i += stride) {
    float4 a = *(const float4*)(s + i);
    float4 b = *(const float4*)(s + i + 4);
    ushort4 o0 = make_ushort4(f2bf_u(a.x), f2bf_u(a.y), f2bf_u(a.z), f2bf_u(a.w));
    ushort4 o1 = make_ushort4(f2bf_u(b.x), f2bf_u(b.y), f2bf_u(b.z), f2bf_u(b.w));
    *(ushort4*)(d + i) = o0;
    *(ushort4*)(d + i + 4) = o1;
  }
}

// ---------------- async global->LDS ----------------
__device__ __forceinline__ void gload16(const void* g, void* l) {
  __builtin_amdgcn_global_load_lds(
      (const __attribute__((address_space(1))) void*)g,
      (__attribute__((address_space(3))) void*)l,
      16, 0, 0);
}

#define BARX() do { asm volatile("" ::: "memory"); __builtin_amdgcn_s_barrier(); asm volatile("" ::: "memory"); } while (0)
#define VMW(n) asm volatile("s_waitcnt vmcnt(" #n ")" ::: "memory")
#define LGKM(n) asm volatile("s_waitcnt lgkmcnt(" #n ")" ::: "memory")

__device__ __forceinline__ void readA(bf16x8 (&fa)[4][2], const char* p, int c0, int c1) {
#pragma unroll
  for (int m = 0; m < 4; ++m) {
    fa[m][0] = *(const bf16x8*)(p + m * 2048 + c0);
    fa[m][1] = *(const bf16x8*)(p + m * 2048 + c1);
  }
}
__device__ __forceinline__ void readB(bf16x8 (&fb)[2][2], const char* p, int c0, int c1) {
#pragma unroll
  for (int n = 0; n < 2; ++n) {
    fb[n][0] = *(const bf16x8*)(p + n * 2048 + c0);
    fb[n][1] = *(const bf16x8*)(p + n * 2048 + c1);
  }
}
__device__ __forceinline__ void mmaQ(f32x4 (&acc)[4][2], const bf16x8 (&fa)[4][2],
                                     const bf16x8 (&fb)[2][2]) {
#pragma unroll
  for (int m = 0; m < 4; ++m)
#pragma unroll
    for (int n = 0; n < 2; ++n)
#pragma unroll
      for (int kk = 0; kk < 2; ++kk)
        acc[m][n] = __builtin_amdgcn_mfma_f32_16x16x32_bf16(fa[m][kk], fb[n][kk], acc[m][n], 0, 0, 0);
}
__device__ __forceinline__ void stageH(const bf16_t* gt, int soff, long rsk, char* lb, int t16) {
  gload16(gt + soff, lb + t16);
  gload16(gt + soff + rsk, lb + 8192 + t16);
}

#define PRIO1() __builtin_amdgcn_s_setprio(1)
#define PRIO0() __builtin_amdgcn_s_setprio(0)

// ---- 256x256 8-phase READ-NEXT bf16 GEMM (round-10 proven, unchanged) ----
// C[m][n] = sum_k A[m][k]*B[n][k]; read@X -> consume@X+1; 4 frag sets; stage=read+2;
// LGKM(4)@ph4/ph8; queue-exact VMW(10) before every barrier; prologue VMW(12).
// EPI 0: bf16 out  1: fp32 out  2: bf16( Xadd + silu(acc) )
template <int EPI>
__global__ __launch_bounds__(512, 2) void gemm256(
    const bf16_t* __restrict__ Abase, const bf16_t* __restrict__ Bbase,
    void* __restrict__ Cout, const float* __restrict__ Xadd,
    int M, int N, int K, long sA, long sB, long sC) {
  __shared__ char smem[131072];
  char* As = smem;            // [A00 | A01 | A10 | A11] x 16KB
  char* Bs = smem + 65536;    // [B00 | B01 | B10 | B11] x 16KB

  const int tid = threadIdx.x;
  const int lane = tid & 63;
  const int wave = tid >> 6;
  const int wm = wave >> 2;   // 0..1  (row stripe)
  const int wn = wave & 3;    // 0..3  (col stripe)
  const int lr = lane & 15;
  const int hi = lane >> 4;

  // bijective XCD swizzle (all our grids are %8==0)
  const int nwg = gridDim.x;
  int wg = blockIdx.x;
  if ((nwg & 7) == 0) wg = (wg & 7) * (nwg >> 3) + (wg >> 3);
  const int nbn = N >> 8;
  const int bm = wg / nbn, bn = wg % nbn;

  const bf16_t* A = Abase + (long)blockIdx.y * sA;
  const bf16_t* B = Bbase + (long)blockIdx.y * sB;
  const bf16_t* A0p = A + (long)(bm * 256) * K;
  const bf16_t* A1p = A0p + (long)128 * K;
  const bf16_t* B0p = B + (long)(bn * 256) * K;
  const bf16_t* B1p = B0p + (long)128 * K;
  const long rsk = (long)64 * K;

  // staging: linear LDS dest, inverse-swizzled global source (3-bit XOR involution)
  const int t16 = tid * 16;
  const int lp = t16 ^ (((t16 >> 7) & 7) << 4);
  const int soff = (lp >> 7) * K + ((lp & 127) >> 1);

  // frag read addressing: row base + swizzled column (kk step applied via XOR 64)
  const int swz = (lr & 7) << 4;
  const int c0 = (hi * 16) ^ swz;
  const int c1 = c0 ^ 64;
  const int aR = (wm * 64 + lr) * 128;
  const int bR = (wn * 32 + lr) * 128;

  f32x4 acc[2][2][4][2] = {};
  bf16x8 fa0[4][2], fa1[4][2], fb0[2][2], fb1[2][2];

  // prologue: stage tiles 0 (b0 regions) and 1 (b1 regions), queue order matters
  stageH(A0p, soff, rsk, As, t16);                // A00  (t0)
  stageH(B0p, soff, rsk, Bs, t16);                // B00  (t0)
  stageH(B1p, soff, rsk, Bs + 16384, t16);        // B01  (t0)
  stageH(A1p, soff, rsk, As + 16384, t16);        // A01  (t0)
  stageH(A0p + 64, soff, rsk, As + 32768, t16);   // A10  (t1)
  stageH(B0p + 64, soff, rsk, Bs + 32768, t16);   // B10  (t1)
  stageH(B1p + 64, soff, rsk, Bs + 49152, t16);   // B11  (t1)
  stageH(A1p + 64, soff, rsk, As + 49152, t16);   // A11  (t1)
  VMW(12);                                        // A00,B00 landed
  BARX();
  readA(fa0, As + aR, c0, c1);                    // A00 frag (for ph1)
  readB(fb0, Bs + bR, c0, c1);                    // B00 frag (for ph1)
  LGKM(0);                                        // drain pre-loop reads (ph1 stages A00)
  VMW(10);                                        // B01 landed (ph1 reads it)
  BARX();

  const int NIT = K >> 7;   // 2 K-tiles (of 64) per iteration
  const int kmask = K - 1;  // K is a power of two
  for (int i = 0; i < NIT; ++i) {
    const int k2 = (128 * i + 128) & kmask;  // next b0 tile (wraps on last iter: dead)
    const int k3 = (128 * i + 192) & kmask;  // next b1 tile

    // ph1: Q00(b0)[fa0,fb0] ; read fb1<-B01 ; stage A00<-k2
    readB(fb1, Bs + 16384 + bR, c0, c1);
    stageH(A0p + k2, soff, rsk, As, t16);
    PRIO1(); mmaQ(acc[0][0], fa0, fb0); PRIO0();
    VMW(10); BARX();
    // ph2: Q01(b0)[fa0,fb1] ; read fa1<-A01 ; stage B00<-k2
    readA(fa1, As + 16384 + aR, c0, c1);
    stageH(B0p + k2, soff, rsk, Bs, t16);
    PRIO1(); mmaQ(acc[0][1], fa0, fb1); PRIO0();
    VMW(10); BARX();
    // ph3: Q11(b0)[fa1,fb1] ; read fa0<-A10 ; stage B01<-k2
    readA(fa0, As + 32768 + aR, c0, c1);
    stageH(B1p + k2, soff, rsk, Bs + 16384, t16);
    PRIO1(); mmaQ(acc[1][1], fa1, fb1); PRIO0();
    VMW(10); BARX();
    // ph4: Q10(b0)[fa1,fb0] ; THEN read fb0<-B10 (reg WAR) ; stage A01<-k2 ; LGKM(4)
    PRIO1(); mmaQ(acc[1][0], fa1, fb0); PRIO0();
    readB(fb0, Bs + 32768 + bR, c0, c1);
    stageH(A1p + k2, soff, rsk, As + 16384, t16);
    LGKM(4);   // drain ph3's fa0 reads (A10 is staged at ph5)
    VMW(10); BARX();
    // ph5: Q00(b1)[fa0,fb0] ; read fb1<-B11 ; stage A10<-k3
    readB(fb1, Bs + 49152 + bR, c0, c1);
    stageH(A0p + k3, soff, rsk, As + 32768, t16);
    PRIO1(); mmaQ(acc[0][0], fa0, fb0); PRIO0();
    VMW(10); BARX();
    // ph6: Q01(b1)[fa0,fb1] ; read fa1<-A11 ; stage B10<-k3
    readA(fa1, As + 49152 + aR, c0, c1);
    stageH(B0p + k3, soff, rsk, Bs + 32768, t16);
    PRIO1(); mmaQ(acc[0][1], fa0, fb1); PRIO0();
    VMW(10); BARX();
    // ph7: Q11(b1)[fa1,fb1] ; read fa0<-A00(next) ; stage B11<-k3
    readA(fa0, As + aR, c0, c1);
    stageH(B1p + k3, soff, rsk, Bs + 49152, t16);
    PRIO1(); mmaQ(acc[1][1], fa1, fb1); PRIO0();
    VMW(10); BARX();
    // ph8: Q10(b1)[fa1,fb0] ; THEN read fb0<-B00(next) ; stage A11<-k3 ; LGKM(4)
    PRIO1(); mmaQ(acc[1][0], fa1, fb0); PRIO0();
    readB(fb0, Bs + bR, c0, c1);
    stageH(A1p + k3, soff, rsk, As + 49152, t16);
    LGKM(4);   // drain ph7's fa0 reads (A00 is staged at next ph1)
    VMW(10); BARX();
  }

  // epilogue: frag elem j -> row += j (D-layout: col=lane&15, row=(lane>>4)*4+j)
  const long cb = (long)blockIdx.y * sC;
#pragma unroll
  for (int mh = 0; mh < 2; ++mh)
#pragma unroll
    for (int nh = 0; nh < 2; ++nh)
#pragma unroll
      for (int m = 0; m < 4; ++m)
#pragma unroll
        for (int n = 0; n < 2; ++n)
#pragma unroll
          for (int j = 0; j < 4; ++j) {
            const int row = bm * 256 + mh * 128 + wm * 64 + m * 16 + hi * 4 + j;
            const int col = bn * 256 + nh * 128 + wn * 32 + n * 16 + lr;
            const long idx = cb + (long)row * N + col;
            const float vv = acc[mh][nh][m][n][j];
            if constexpr (EPI == 0) {
              ((uint16_t*)Cout)[idx] = f2bf_u(vv);
            } else if constexpr (EPI == 1) {
              ((float*)Cout)[idx] = vv;
            } else {
              const float sl = vv / (1.f + __expf(-vv));
              ((uint16_t*)Cout)[idx] = f2bf_u(Xadd[idx] + sl);
            }
          }
}

// ------------- per-row (max, 1/sum(exp)) stats over bf16 rows of width 4096 -------------
__global__ __launch_bounds__(256) void rowstat4096_bf16(const uint16_t* __restrict__ in,
                                                        float2* __restrict__ stats) {
  const long row = blockIdx.x;
  const uint16_t* r = in + row * 4096;
  const int tid = threadIdx.x;
  uint32_t w[8];
  *(uint4*)(w) = *(const uint4*)(r + tid * 16);
  *(uint4*)(w + 4) = *(const uint4*)(r + tid * 16 + 8);
  float v[16];
#pragma unroll
  for (int j = 0; j < 8; ++j) {
    v[2 * j] = bfu2f(w[j] & 0xFFFFu);
    v[2 * j + 1] = bfu2f(w[j] >> 16);
  }
  float m = v[0];
#pragma unroll
  for (int j = 1; j < 16; ++j) m = fmaxf(m, v[j]);
#pragma unroll
  for (int o = 32; o; o >>= 1) m = fmaxf(m, __shfl_xor(m, o));
  __shared__ float red[8];
  if ((tid & 63) == 0) red[tid >> 6] = m;
  __syncthreads();
  m = fmaxf(fmaxf(red[0], red[1]), fmaxf(red[2], red[3]));
  float s = 0.f;
#pragma unroll
  for (int j = 0; j < 16; ++j) s += __expf(v[j] - m);
#pragma unroll
  for (int o = 32; o; o >>= 1) s += __shfl_xor(s, o);
  if ((tid & 63) == 0) red[4 + (tid >> 6)] = s;
  __syncthreads();
  if (tid == 0) {
    s = (red[4] + red[5]) + (red[6] + red[7]);
    stats[row] = make_float2(m, 1.f / s);
  }
}

// ------ fused softmax + transpose (bf16 in/out): out[b][e][d] = sm(in[b])[d][e] ------
__global__ __launch_bounds__(256) void transposeSM_bf16(const uint16_t* __restrict__ inB,
                                                        const float2* __restrict__ statsB,
                                                        uint16_t* __restrict__ outB) {
  const int b = blockIdx.z;
  const uint16_t* in = inB + (long)b * (4096L * 4096);
  const float2* stats = statsB + (long)b * 4096;
  uint16_t* out = outB + (long)b * (4096L * 4096);
  __shared__ uint16_t t[64][68];
  __shared__ float2 st[64];
  const int tid = threadIdx.x;
  const int bx = blockIdx.x, by = blockIdx.y;
  if (tid < 64) st[tid] = stats[by * 64 + tid];
  __syncthreads();
  const int tr = tid >> 4;
  const int tc4 = (tid & 15) * 4;
#pragma unroll
  for (int i = 0; i < 4; ++i) {
    const int r = tr + i * 16;
    const float2 ms = st[r];
    ushort4 u = *(const ushort4*)&in[(long)(by * 64 + r) * 4096 + bx * 64 + tc4];
    t[r][tc4 + 0] = f2bf_u(__expf(bfu2f(u.x) - ms.x) * ms.y);
    t[r][tc4 + 1] = f2bf_u(__expf(bfu2f(u.y) - ms.x) * ms.y);
    t[r][tc4 + 2] = f2bf_u(__expf(bfu2f(u.z) - ms.x) * ms.y);
    t[r][tc4 + 3] = f2bf_u(__expf(bfu2f(u.w) - ms.x) * ms.y);
  }
  __syncthreads();
#pragma unroll
  for (int i = 0; i < 4; ++i) {
    const int oc = tr + i * 16;
    ushort4 v = make_ushort4(t[tc4 + 0][oc], t[tc4 + 1][oc], t[tc4 + 2][oc], t[tc4 + 3][oc]);
    *(ushort4*)&out[(long)(bx * 64 + oc) * 4096 + by * 64 + tc4] = v;
  }
}

// ---------------- row softmax (bf16 in, bf16 out, width 4096) ----------------
__global__ __launch_bounds__(256) void softmax_row4096_bf16(const uint16_t* __restrict__ in,
                                                            uint16_t* __restrict__ out) {
  const long row = blockIdx.x;
  const uint16_t* r = in + row * 4096;
  const int tid = threadIdx.x;
  uint32_t w[8];
  *(uint4*)(w) = *(const uint4*)(r + tid * 16);
  *(uint4*)(w + 4) = *(const uint4*)(r + tid * 16 + 8);
  float v[16];
#pragma unroll
  for (int j = 0; j < 8; ++j) {
    v[2 * j] = bfu2f(w[j] & 0xFFFFu);
    v[2 * j + 1] = bfu2f(w[j] >> 16);
  }
  float m = v[0];
#pragma unroll
  for (int j = 1; j < 16; ++j) m = fmaxf(m, v[j]);
#pragma unroll
  for (int o = 32; o; o >>= 1) m = fmaxf(m, __shfl_xor(m, o));
  __shared__ float red[8];
  if ((tid & 63) == 0) red[tid >> 6] = m;
  __syncthreads();
  m = fmaxf(fmaxf(red[0], red[1]), fmaxf(red[2], red[3]));
  float s = 0.f;
#pragma unroll
  for (int j = 0; j < 16; ++j) { v[j] = __expf(v[j] - m); s += v[j]; }
#pragma unroll
  for (int o = 32; o; o >>= 1) s += __shfl_xor(s, o);
  if ((tid & 63) == 0) red[4 + (tid >> 6)] = s;
  __syncthreads();
  s = (red[4] + red[5]) + (red[6] + red[7]);
  float inv = 1.f / s;
#pragma unroll
  for (int i = 0; i < 4; ++i) {
    ushort4 u = make_ushort4(f2bf_u(v[i * 4 + 0] * inv), f2bf_u(v[i * 4 + 1] * inv),
                             f2bf_u(v[i * 4 + 2] * inv), f2bf_u(v[i * 4 + 3] * inv));
    *(ushort4*)(out + row * 4096 + tid * 16 + i * 4) = u;
  }
}

// ---------------- host ----------------
extern "C" void kernel_launch(void* const* d_in, const int* in_sizes, int n_in,
                              void* d_out, int out_size, void* d_ws, size_t ws_size,
                              hipStream_t stream) {
  const float* x  = (const float*)d_in[0];
  const float* W1 = (const float*)d_in[1];
  const float* W2 = (const float*)d_in[2];
  const float* W3 = (const float*)d_in[3];
  const float* W4 = (const float*)d_in[4];
  const float* Wo = (const float*)d_in[5];

  char* ws = (char*)d_ws;
  const long SD  = (long)SEQ * DIM;   // 8,388,608
  const long BSD = (long)NB * SD;
  const long DD  = (long)DIM * DIM;   // 16,777,216

  // workspace layout (436,207,616 bytes == proven footprint)
  bf16_t* xbf  = (bf16_t*)(ws + 0L);           // 67 MB : x bf16; later y_in bf16
  bf16_t* xW   = (bf16_t*)(ws + 67108864L);    // 134 MB: [b][ xA^T | xB^T ]; later xO_sm(lo) + Wo(hi)
  bf16_t* R3   = (bf16_t*)(ws + 201326592L);   // 67 MB : W1||W2 bf16; later xC bf16
  bf16_t* Wbf  = (bf16_t*)(ws + 268435456L);   // 33.5MB: stats during sq; then W3 bf16
  bf16_t* sqmT = (bf16_t*)(ws + 301989888L);   // 134 MB: softmax(sq)^T bf16 [4][e][d]
  float2* stats = (float2*)Wbf;                // 16384 x float2, dead before W3 cvt
  // W4 parks in d_out's upper half (dead between transposeSM and the final out-GEMM write)
  uint16_t* W4bf = (uint16_t*)((char*)d_out + 67108864L);
  bf16_t*   Wobf = xW + BSD;                   // xW upper half, dead after sq GEMM
  (void)ws_size; (void)in_sizes; (void)n_in; (void)out_size;

  // head cvts: x -> xbf, W1 -> R3, W2 -> R3+DD   (one launch)
  cvt3_f32_bf16_k<<<dim3(1024, 3), 256, 0, stream>>>(
      x, (uint16_t*)xbf, BSD, W1, (uint16_t*)R3, DD, W2, (uint16_t*)(R3 + DD), DD);

  // merged G1+G2: xW[b] = (W1||W2) @ x_b^T   [b][2*4096][2048] bf16
  gemm256<0><<<dim3(256, 4), 512, 0, stream>>>(R3, xbf, (void*)xW, nullptr,
                                               2 * DIM, SEQ, DIM, 0, SD, 2 * SD);

  // batched sq: SQ_bf16[b][d][e] = xA_b^T @ xB_b  -> d_out (134 MB)
  gemm256<0><<<dim3(256, 4), 512, 0, stream>>>(xW, xW + SD, d_out, nullptr,
                                               DIM, DIM, SEQ, 2 * SD, 2 * SD, DD);
  // row stats over all 4*4096 rows
  rowstat4096_bf16<<<NB * DIM, 256, 0, stream>>>((const uint16_t*)d_out, stats);
  // fused softmax+transpose -> sqmT[b][e][d]
  transposeSM_bf16<<<dim3(64, 64, 4), 256, 0, stream>>>((const uint16_t*)d_out, stats,
                                                        (uint16_t*)sqmT);

  // tail cvts: W3 -> Wbf (stats dead), W4 -> d_out upper half, Wo -> xW upper half
  cvt3_f32_bf16_k<<<dim3(1024, 3), 256, 0, stream>>>(
      W3, (uint16_t*)Wbf, DD, W4, W4bf, DD, Wo, (uint16_t*)Wobf, DD);

  // xC = x @ W3^T  -> R3 (bf16, batch folded into M)
  gemm256<0><<<dim3(512, 1), 512, 0, stream>>>(xbf, Wbf, (void*)R3, nullptr,
                                               NB * SEQ, DIM, DIM, 0, 0, 0);

  // xO[b][s][e] = xC_b @ sqmT_b^T  -> d_out lower half (bf16; W4 in upper half untouched)
  gemm256<0><<<dim3(128, 4), 512, 0, stream>>>(R3, sqmT, d_out, nullptr,
                                               SEQ, DIM, DIM, SD, DD, SD);
  // softmax rows of xO -> xO_sm bf16 into xW lower half
  softmax_row4096_bf16<<<NB * SEQ, 256, 0, stream>>>((const uint16_t*)d_out, (uint16_t*)xW);

  // y_in = bf16( x + silu(xO_sm @ W4^T) ) -> xbf
  gemm256<2><<<dim3(512, 1), 512, 0, stream>>>(xW, (const bf16_t*)W4bf, (void*)xbf, x,
                                               NB * SEQ, DIM, DIM, 0, 0, 0);

  // out = y_in @ Wo^T (fp32) -> d_out (overwrites W4 slot last)
  gemm256<1><<<dim3(512, 1), 512, 0, stream>>>(xbf, Wobf, d_out, nullptr,
                                               NB * SEQ, DIM, DIM, 0, 0, 0);
}